// Round 4
// baseline (260.961 us; speedup 1.0000x reference)
//
#include <hip/hip_runtime.h>
#include <cstdint>

#define N_IMG 32
#define C_IN 128
#define H_IN 56
#define W_IN 56
#define K_OUT 256
#define HW (H_IN * W_IN)            // 3136
#define M_TOTAL (N_IMG * HW)        // 100352
#define XP_H 58
#define XP_W 58
#define XP_ELEMS (N_IMG * XP_H * XP_W * C_IN)   // 13,778,944 bf16
#define WT_ELEMS (9 * K_OUT * C_IN)             // 294,912 bf16
#define N_STAGE 36                  // 9 rs positions x 4 c-chunks of 32

typedef __bf16 bf16x8 __attribute__((ext_vector_type(8)));
typedef float f32x4 __attribute__((ext_vector_type(4)));

__device__ __align__(16) unsigned short g_xp[XP_ELEMS];  // padded NHWC bf16 input
__device__ __align__(16) unsigned short g_wt[WT_ELEMS];  // wt[rs][k][c] bf16 weights

static __device__ __forceinline__ unsigned short f2bf(float f) {
    unsigned int u = __builtin_bit_cast(unsigned int, f);
    u += 0x7fffu + ((u >> 16) & 1u);   // RNE
    return (unsigned short)(u >> 16);
}

// async global->LDS, 16 bytes per lane; LDS dest = wave-uniform base + lane*16
static __device__ __forceinline__ void async_copy16(const unsigned short* g, unsigned short* l) {
    auto gp = (const __attribute__((address_space(1))) unsigned int*)g;
    auto lp = (__attribute__((address_space(3))) unsigned int*)l;
    __builtin_amdgcn_global_load_lds(gp, lp, 16, 0, 0);
}

// ---------------- prep kernel 1: NCHW fp32 -> padded NHWC bf16 (+border zero) --
__global__ __launch_bounds__(256) void xpose_x(const float* __restrict__ x) {
    __shared__ float tile[C_IN * 57];     // [c][w]; stride 57 -> 4-way banks max
    const int h = blockIdx.x;
    const int n = blockIdx.y;
    const int tid = threadIdx.x;

    if (tid < 32) {                        // zero w-borders of padded row h+1
        int col = (tid >> 4) * (XP_W - 1);
        int q = tid & 15;
        uint4* dst = (uint4*)(g_xp + ((size_t)(n * XP_H + h + 1) * XP_W + col) * C_IN) + q;
        *dst = uint4{0u, 0u, 0u, 0u};
    }
    if (h == 0 || h == H_IN - 1) {         // edge blocks zero top/bottom rows
        int hp = (h == 0) ? 0 : XP_H - 1;
        uint4* base = (uint4*)(g_xp + ((size_t)(n * XP_H + hp) * XP_W) * C_IN);
        for (int q = tid; q < (XP_W * C_IN) / 8; q += 256) base[q] = uint4{0u, 0u, 0u, 0u};
    }

#pragma unroll
    for (int i = 0; i < 28; i++) {        // 28*256 = 128*56
        int e = i * 256 + tid;
        int c = e / 56;
        int w = e - c * 56;
        tile[c * 57 + w] = x[((n * C_IN + c) * H_IN + h) * W_IN + w];
    }
    __syncthreads();
    unsigned int* outp = (unsigned int*)g_xp;
#pragma unroll
    for (int i = 0; i < 14; i++) {        // 14*256 = 56*64 (pairs of c)
        int u = i * 256 + tid;
        int w = u >> 6;
        int cp = u & 63;
        float a = tile[(2 * cp) * 57 + w];
        float b = tile[(2 * cp + 1) * 57 + w];
        unsigned int pk = (unsigned int)f2bf(a) | ((unsigned int)f2bf(b) << 16);
        int idx = ((n * XP_H + h + 1) * XP_W + (w + 1)) * C_IN + 2 * cp;
        outp[idx >> 1] = pk;
    }
}

// ---------------- prep kernel 2: OIHW fp32 -> wt[rs][k][c] bf16 ----------------
__global__ __launch_bounds__(256) void xpose_w(const float* __restrict__ w) {
    int e = blockIdx.x * 256 + threadIdx.x;
    int rr = e >> 15;
    int rem = e & 32767;
    int k = rem >> 7;
    int c = rem & 127;
    g_wt[e] = f2bf(w[(k * C_IN + c) * 9 + rr]);
}

// ---------------- main: implicit-GEMM bf16 MFMA, dbuf + XOR bank swizzle -------
// 128x128 block tile, BK=32, 4 waves (2x2), 4x4 accs/wave.
// LDS layout swizzle: global c-group g of row ml lives at LDS slot (g ^ (ml&3)).
// Staged via global_load_lds (dest fixed = base + lane*16), so the swizzle is
// applied to WHICH global chunk each lane fetches. Fragment reads then start at
// banks {0,8,16,24} across lr&3 -> uniform 2 words/bank (was 8/bank on 8 banks,
// SQ_LDS_BANK_CONFLICT showed exactly +4 phases per ds_read_b128).
__global__ __launch_bounds__(256, 4) void conv_main(float* __restrict__ out) {
    __shared__ __align__(16) unsigned short As[2][128 * 32];
    __shared__ __align__(16) unsigned short Bs[2][128 * 32];
    const unsigned short* xp = g_xp;
    const unsigned short* wt = g_wt;

    const int tid = threadIdx.x;
    const int k0 = blockIdx.x * 128;     // x = k-block: the 2 blocks sharing an
    const int m0 = blockIdx.y * 128;     // A-tile are dispatch-adjacent (L2 reuse)
    const int wave = tid >> 6, lane = tid & 63;
    const int wm = (wave & 1) * 64;
    const int wn = (wave >> 1) * 64;
    const int lr = lane & 15;
    const int lq = lane >> 4;

    // staging: unit u = j*256+tid -> LDS slot (ml=u>>2, cgl=u&3) at byte u*16;
    // lane fetches global c-group cgl ^ (ml&3)
    int a_base[2], b_base[2], lds_off[2];
#pragma unroll
    for (int j = 0; j < 2; j++) {
        int u = j * 256 + tid;
        int ml = u >> 2;
        int cgl = u & 3;
        int cg = cgl ^ (ml & 3);         // swizzled global c-group
        int p = m0 + ml;
        int n = p / HW;
        int rem = p - n * HW;
        int h = rem / W_IN;
        int w = rem - h * W_IN;
        a_base[j] = ((n * XP_H + h) * XP_W + w) * C_IN + cg * 8;
        b_base[j] = (k0 + ml) * C_IN + cg * 8;
        lds_off[j] = (j * 256 + wave * 64) * 8;   // wave-uniform base (+lane*16B)
    }

    auto issue = [&](int s, int buf) {
        int rs = s >> 2;
        int c0 = (s & 3) << 5;
        int r = (rs * 11) >> 5;          // rs/3
        int sc = rs - r * 3;             // rs%3
        int a_off = (r * XP_W + sc) * C_IN + c0;
        int b_off = rs * (K_OUT * C_IN) + c0;
#pragma unroll
        for (int j = 0; j < 2; j++) {
            async_copy16(xp + a_base[j] + a_off, &As[buf][0] + lds_off[j]);
            async_copy16(wt + b_base[j] + b_off, &Bs[buf][0] + lds_off[j]);
        }
    };

    f32x4 acc[4][4];
#pragma unroll
    for (int mi = 0; mi < 4; mi++)
#pragma unroll
        for (int ni = 0; ni < 4; ni++)
            acc[mi][ni] = f32x4{0.f, 0.f, 0.f, 0.f};

    // fragment LDS slot for k-group lq of row (.. + lr): lq ^ (lr&3)
    const int a_slot = (lq ^ (lr & 3)) * 8;

    issue(0, 0);
#pragma unroll 2
    for (int s = 0; s < N_STAGE; s++) {
        const int cb = s & 1;
        __syncthreads();                  // drains loads(s); LDS(s-1) reads done
        if (s + 1 < N_STAGE) issue(s + 1, cb ^ 1);
        bf16x8 af[4], bfr[4];
#pragma unroll
        for (int i = 0; i < 4; i++)
            af[i] = *(const bf16x8*)(&As[cb][0] + (wm + i * 16 + lr) * 32 + a_slot);
#pragma unroll
        for (int i = 0; i < 4; i++)
            bfr[i] = *(const bf16x8*)(&Bs[cb][0] + (wn + i * 16 + lr) * 32 + a_slot);
#pragma unroll
        for (int mi = 0; mi < 4; mi++)
#pragma unroll
            for (int ni = 0; ni < 4; ni++)
                acc[mi][ni] = __builtin_amdgcn_mfma_f32_16x16x32_bf16(
                    af[mi], bfr[ni], acc[mi][ni], 0, 0, 0);
    }

    // epilogue: lane's float4 = 4 consecutive pixels at fixed out-channel k
#pragma unroll
    for (int mi = 0; mi < 4; mi++) {
        int p = m0 + wm + mi * 16 + lq * 4;
        int n = p / HW;
        int off = p - n * HW;
#pragma unroll
        for (int ni = 0; ni < 4; ni++) {
            int k = k0 + wn + ni * 16 + lr;
            *(f32x4*)(out + (n * K_OUT + k) * HW + off) = acc[mi][ni];
        }
    }
}

extern "C" void kernel_launch(void* const* d_in, const int* in_sizes, int n_in,
                              void* d_out, int out_size, void* d_ws, size_t ws_size,
                              hipStream_t stream) {
    const float* x = (const float*)d_in[0];
    const float* w = (const float*)d_in[1];
    float* out = (float*)d_out;

    hipLaunchKernelGGL(xpose_x, dim3(H_IN, N_IMG), dim3(256), 0, stream, x);
    hipLaunchKernelGGL(xpose_w, dim3(WT_ELEMS / 256), dim3(256), 0, stream, w);
    hipLaunchKernelGGL(conv_main, dim3(K_OUT / 128, M_TOTAL / 128), dim3(256), 0, stream, out);
}